// Round 2
// baseline (58.650 us; speedup 1.0000x reference)
//
#include <hip/hip_runtime.h>
#include <hip/hip_bf16.h>
#include <stdint.h>

// Problem constants (fixed by the reference)
#define B_SZ 8192
#define D_SZ 256
#define R_SZ 8
#define N_SZ 1024
#define C_SZ (B_SZ / R_SZ)          // 1024
#define CN   (C_SZ * N_SZ)          // 1048576
#define L_SZ (B_SZ + 2 * R_SZ * CN) // 16785408 (logits length)
#define BD   (B_SZ * D_SZ)          // elements per ws array

typedef short bf16x8 __attribute__((ext_vector_type(8)));
typedef float f32x4  __attribute__((ext_vector_type(4)));

static __device__ __forceinline__ unsigned short f2bf(float f) {
  unsigned u = __float_as_uint(f);
  u += 0x7FFFu + ((u >> 16) & 1u);   // RNE
  return (unsigned short)(u >> 16);
}
static __device__ __forceinline__ float bf2f(unsigned short h) {
  return __uint_as_float(((unsigned)h) << 16);
}
static __device__ __forceinline__ float sigmoidf_(float x) {
  return 1.0f / (1.0f + __expf(-x));
}
static __device__ __forceinline__ void gload16(const void* g, void* l) {
  __builtin_amdgcn_global_load_lds(
      (const __attribute__((address_space(1))) void*)g,
      (__attribute__((address_space(3))) void*)l, 16, 0, 0);
}

// ---------------------------------------------------------------------------
// Phase 1: F-reduce emb -> lhs/rhs, split into bf16 hi+lo in ws, pos logits.
// One wave per batch row i. 2048 blocks x 256 threads. (~8 us, BW-bound.)
// ---------------------------------------------------------------------------
__global__ __launch_bounds__(256) void prep_kernel(
    const float* __restrict__ emb, const float* __restrict__ trans,
    const int* __restrict__ rels, float* __restrict__ out,
    unsigned short* __restrict__ ws) {
  unsigned short* lhs_hi = ws;
  unsigned short* lhs_lo = ws + (size_t)BD;
  unsigned short* rhs_hi = ws + (size_t)2 * BD;
  unsigned short* rhs_lo = ws + (size_t)3 * BD;

  int wave = threadIdx.x >> 6;
  int lane = threadIdx.x & 63;
  int i = blockIdx.x * 4 + wave;            // 0..B-1

  const float4* emb4 = (const float4*)emb;  // emb row j = 128 float4 (F*D=512 f32)
  size_t bl = (size_t)(2 * i) * 128;
  size_t br = (size_t)(2 * i + 1) * 128;
  float4 a0 = emb4[bl + lane];
  float4 a1 = emb4[bl + 64 + lane];
  float4 b0 = emb4[br + lane];
  float4 b1 = emb4[br + 64 + lane];
  float lh[4] = {a0.x + a1.x, a0.y + a1.y, a0.z + a1.z, a0.w + a1.w};
  float rh[4] = {b0.x + b1.x, b0.y + b1.y, b0.z + b1.z, b0.w + b1.w};

  int rel = rels[i];
  float4 tv = ((const float4*)trans)[rel * 64 + lane];
  float tt[4] = {tv.x, tv.y, tv.z, tv.w};

  float p = 0.f;
#pragma unroll
  for (int j = 0; j < 4; ++j) p += lh[j] * (rh[j] + tt[j]);
#pragma unroll
  for (int off = 32; off; off >>= 1) p += __shfl_xor(p, off, 64);
  if (lane == 0) {
    out[i] = p;
    out[(size_t)L_SZ + i] = sigmoidf_(p);
  }

  unsigned short h[4], l[4];
#pragma unroll
  for (int j = 0; j < 4; ++j) {
    h[j] = f2bf(lh[j]);
    l[j] = f2bf(lh[j] - bf2f(h[j]));
  }
  *(ushort4*)(lhs_hi + (size_t)i * 256 + lane * 4) = make_ushort4(h[0], h[1], h[2], h[3]);
  *(ushort4*)(lhs_lo + (size_t)i * 256 + lane * 4) = make_ushort4(l[0], l[1], l[2], l[3]);
#pragma unroll
  for (int j = 0; j < 4; ++j) {
    h[j] = f2bf(rh[j]);
    l[j] = f2bf(rh[j] - bf2f(h[j]));
  }
  *(ushort4*)(rhs_hi + (size_t)i * 256 + lane * 4) = make_ushort4(h[0], h[1], h[2], h[3]);
  *(ushort4*)(rhs_lo + (size_t)i * 256 + lane * 4) = make_ushort4(l[0], l[1], l[2], l[3]);
}

// ---------------------------------------------------------------------------
// Phase 2: gather-GEMM negatives as a K=768 bf16 GEMM (3 segments x K=256):
//   seg0: Ah*Bh   seg1: Al*Bh   seg2: Ah*Bl
// BM=BN=256, BK=32 (24 K-tiles), 8 waves (2x4), acc[8][4], dbuf LDS 64 KB,
// grid = 256 blocks = 1/CU. Counted-vmcnt pipeline with raw s_barrier:
//   STAGE(next) ; vmcnt(4) ; bar ; COMPUTE(cur) ; bar
// XOR swizzle: source chunk ^= (row>>1)&3 (linear global_load_lds dest),
// same XOR on ds_read_b128 -> 2-way (free). XCD swizzle: 32 logical blocks
// (= one relation r, 2 MB of ws) per XCD -> L2-resident staging.
// ---------------------------------------------------------------------------
__global__ __launch_bounds__(512, 2) void negs_kernel(
    const unsigned short* __restrict__ ws,
    const int* __restrict__ order,
    const int* __restrict__ negL, const int* __restrict__ negR,
    float* __restrict__ out) {
  __shared__ unsigned short lds[2][16384];  // per buf: A 16KB @0, B 16KB @+16384; 64 KB total

  const unsigned short* lhs_hi = ws;
  const unsigned short* lhs_lo = ws + (size_t)BD;
  const unsigned short* rhs_hi = ws + (size_t)2 * BD;
  const unsigned short* rhs_lo = ws + (size_t)3 * BD;

  int hw = blockIdx.x;
  int bid = (hw & 7) * 32 + (hw >> 3);   // bijective: 256 = 8 XCD x 32
  int ntile = bid & 3;
  int ctile = (bid >> 2) & 3;
  int side  = (bid >> 4) & 1;
  int r     = bid >> 5;

  int t = threadIdx.x;
  int wave = t >> 6, lane = t & 63;
  int wrow = wave >> 2, wcol = wave & 3;

  // side 0: negs_lhs = s_rhs . samp_lhs^T ; side 1: negs_rhs = s_lhs . samp_rhs^T
  const unsigned short* aHi = side ? lhs_hi : rhs_hi;
  const unsigned short* aLo = side ? lhs_lo : rhs_lo;
  const unsigned short* bHi = side ? rhs_hi : lhs_hi;
  const unsigned short* bLo = side ? rhs_lo : lhs_lo;
  const int* negp = side ? negR : negL;

  // Staging: thread t covers LDS slot (row = op*128 + t>>2, chunk = t&3) for
  // op in {0,1}; source chunk is inverse-swizzled: (t&3) ^ ((row>>1)&3).
  unsigned aOff[2], bOff[2];
  {
    unsigned srcsw = (unsigned)(((t & 3) ^ ((t >> 3) & 3)) << 4);
#pragma unroll
    for (int op = 0; op < 2; ++op) {
      int ar = order[r * C_SZ + ctile * 256 + op * 128 + (t >> 2)];
      int br = negp[r * N_SZ + ntile * 256 + op * 128 + (t >> 2)];
      aOff[op] = (unsigned)ar * 512u + srcsw;
      bOff[op] = (unsigned)br * 512u + srcsw;
    }
  }
  unsigned ldsw = (unsigned)(wave << 10);  // wave-uniform; HW adds lane*16

  auto STAGE = [&](int buf, int kt) {
    int seg = kt >> 3, kc = kt & 7;                 // seg 0..2, kc 0..7 (64B col slice)
    const char* pa = (const char*)(seg == 1 ? aLo : aHi) + kc * 64;
    const char* pb = (const char*)(seg == 2 ? bLo : bHi) + kc * 64;
    char* lbase = (char*)&lds[buf][0];
#pragma unroll
    for (int op = 0; op < 2; ++op)
      gload16(pa + aOff[op], lbase + op * 8192 + ldsw);
#pragma unroll
    for (int op = 0; op < 2; ++op)
      gload16(pb + bOff[op], lbase + 16384 + op * 8192 + ldsw);
  };

  f32x4 acc[8][4] = {};

  auto COMPUTE = [&](int buf) {
    const char* Ab = (const char*)&lds[buf][0];
    const char* Bb = Ab + 16384;
    int lx = lane & 15;
    int kch = (((lane >> 4) ^ ((lane >> 1) & 3)) << 4);  // swizzled 16B chunk
    bf16x8 af[8], bf[4];
#pragma unroll
    for (int mi = 0; mi < 8; ++mi)
      af[mi] = *(const bf16x8*)(Ab + (wrow * 128 + mi * 16 + lx) * 64 + kch);
#pragma unroll
    for (int ni = 0; ni < 4; ++ni)
      bf[ni] = *(const bf16x8*)(Bb + (wcol * 64 + ni * 16 + lx) * 64 + kch);
#pragma unroll
    for (int mi = 0; mi < 8; ++mi)
#pragma unroll
      for (int ni = 0; ni < 4; ++ni)
        acc[mi][ni] = __builtin_amdgcn_mfma_f32_16x16x32_bf16(af[mi], bf[ni], acc[mi][ni], 0, 0, 0);
  };

  STAGE(0, 0);
  int cur = 0;
  for (int kt = 0; kt < 23; ++kt) {
    STAGE(cur ^ 1, kt + 1);
    asm volatile("s_waitcnt vmcnt(4)" ::: "memory");  // cur's 4 landed; next's 4 in flight
    asm volatile("s_barrier" ::: "memory");
    COMPUTE(cur);
    asm volatile("s_barrier" ::: "memory");           // all reads of cur done
    cur ^= 1;
  }
  asm volatile("s_waitcnt vmcnt(0)" ::: "memory");
  asm volatile("s_barrier" ::: "memory");
  COMPUTE(cur);

  // Epilogue: C/D layout col = lane&15, row = (lane>>4)*4 + j.
  size_t obase = (size_t)B_SZ + ((size_t)(r * 2 + side)) * CN;
  int gcb = ntile * 256 + wcol * 64 + (lane & 15);
  int grb = ctile * 256 + wrow * 128 + ((lane >> 4) << 2);
#pragma unroll
  for (int mi = 0; mi < 8; ++mi) {
#pragma unroll
    for (int ni = 0; ni < 4; ++ni) {
      int gc = gcb + ni * 16;
#pragma unroll
      for (int j = 0; j < 4; ++j) {
        int gr = grb + mi * 16 + j;
        size_t idx = obase + (size_t)gr * N_SZ + gc;
        float v = acc[mi][ni][j];
        out[idx] = v;
        out[(size_t)L_SZ + idx] = sigmoidf_(v);
      }
    }
  }
}

// ---------------------------------------------------------------------------
extern "C" void kernel_launch(void* const* d_in, const int* in_sizes, int n_in,
                              void* d_out, int out_size, void* d_ws, size_t ws_size,
                              hipStream_t stream) {
  const float* emb   = (const float*)d_in[0];
  const float* trans = (const float*)d_in[1];
  const int*   rels  = (const int*)d_in[2];
  const int*   order = (const int*)d_in[3];
  const int*   negL  = (const int*)d_in[4];
  const int*   negR  = (const int*)d_in[5];
  float* out = (float*)d_out;
  unsigned short* ws = (unsigned short*)d_ws;  // 4 * B*D * 2B = 16 MB

  prep_kernel<<<B_SZ / 4, 256, 0, stream>>>(emb, trans, rels, out, ws);
  negs_kernel<<<256, 512, 0, stream>>>(ws, order, negL, negR, out);
}